// Round 16
// baseline (226.672 us; speedup 1.0000x reference)
//
#include <hip/hip_runtime.h>
#include <float.h>
#include <math.h>

// KNNAttention: b=4, l=2048, d=1024, h=16, dh=64, n_mem=1000
#define BATCH 4
#define SEQ   2048
#define DIM   1024
#define NHEAD 16
#define DHEAD 64
#define NMEM  1000
#define NPAD  1024          // padded memory slots
#define ROWS  (BATCH*SEQ)   // 8192
// qp pre-scale: 0.125 * log2(e); softmax becomes exp2(S + log2(count))
#define QSCALE 0.18033688011112042f
// rescore window (scaled-score units): ~7.4 sigma of 1-product score noise
#define RESCORE_DELTA 0.10f

typedef __attribute__((ext_vector_type(8))) __bf16 bf16x8;
typedef __attribute__((ext_vector_type(4))) __bf16 bf16x4;
typedef __attribute__((ext_vector_type(4))) float  f32x4;

static __device__ inline f32x4 mfma16(bf16x8 a, bf16x8 b, f32x4 c) {
  return __builtin_amdgcn_mfma_f32_16x16x32_bf16(a, b, c, 0, 0, 0);
}

// async global->LDS, 16B per lane. LDS dest must be wave-uniform base (+lane*16).
#define GLOAD16(g, l) __builtin_amdgcn_global_load_lds( \
    (const __attribute__((address_space(1))) unsigned int*)(g), \
    (__attribute__((address_space(3))) unsigned int*)(l), 16, 0, 0)

enum { MODE_C = 0, MODE_HILO = 1, MODE_ARGMAX = 2, MODE_KV = 3 };

// ---------------------------------------------------------------------------
// Fused split-bf16 GEMM (verified rounds 2-14): C = A * B^T, up to 3 products.
// Double-buffered staging. MODE_ARGMAX (NPROD=1): per-row TOP-2 per 64-col
// half -> pv/pi[32][ROWS] candidates for exact rescore.
// ---------------------------------------------------------------------------
template<int NPROD, int MODE>
__global__ __launch_bounds__(256) void gemm3(
    const __bf16* __restrict__ Ah, const __bf16* __restrict__ Al,
    const __bf16* __restrict__ Bh, const __bf16* __restrict__ Bl,
    int rowsPerZ, long bStrideZ,
    float* __restrict__ C, __bf16* __restrict__ Oh, __bf16* __restrict__ Ol,
    float* __restrict__ pv, int* __restrict__ pi)
{
  extern __shared__ char smem[];
  const int t = threadIdx.x;
  const int w = t >> 6, lane = t & 63, l15 = lane & 15, g = lane >> 4;
  const int wr = w >> 1, wc = w & 1;
  const int m0 = blockIdx.z * rowsPerZ + blockIdx.x * 128;
  const int n0 = blockIdx.y * 128;
  const __bf16* Bh_b = Bh + (size_t)blockIdx.z * bStrideZ;
  const __bf16* Bl_b = (NPROD == 3) ? (Bl + (size_t)blockIdx.z * bStrideZ) : (const __bf16*)0;

  constexpr int SB   = (NPROD == 3) ? 32768 : 16384;
  constexpr int BOFF = (NPROD == 3) ? 16384 : 8192;

  f32x4 acc[4][4];
  #pragma unroll
  for (int i = 0; i < 4; ++i)
    #pragma unroll
    for (int j = 0; j < 4; ++j) acc[i][j] = (f32x4){0.f, 0.f, 0.f, 0.f};

  auto STAGE = [&](int buf, int k0) {
    char* base = smem + buf * SB;
    #pragma unroll
    for (int i = 0; i < 2; ++i) {
      int c = i * 256 + t;
      int r = c >> 2, s = c & 3;
      int sl = s ^ (r & 3);
      GLOAD16(&Ah[(size_t)(m0 + r) * DIM + k0 + sl * 8], base + i * 4096 + w * 1024);
      if (NPROD == 3)
        GLOAD16(&Al[(size_t)(m0 + r) * DIM + k0 + sl * 8], base + 8192 + i * 4096 + w * 1024);
    }
    char* bB = base + BOFF;
    #pragma unroll
    for (int i = 0; i < 2; ++i) {
      int c = i * 256 + t;
      int r = c >> 2, s = c & 3;
      int sl = s ^ (r & 3);
      GLOAD16(&Bh_b[(size_t)(n0 + r) * DIM + k0 + sl * 8], bB + i * 4096 + w * 1024);
      if (NPROD == 3)
        GLOAD16(&Bl_b[(size_t)(n0 + r) * DIM + k0 + sl * 8], bB + 8192 + i * 4096 + w * 1024);
    }
  };

  STAGE(0, 0);
  __syncthreads();
  int cur = 0;

  for (int k0 = 0; k0 < DIM; k0 += 32) {
    if (k0 + 32 < DIM) STAGE(cur ^ 1, k0 + 32);   // prefetch next tile

    char* base = smem + cur * SB;
    char* sA   = base;
    char* sAl  = base + 8192;
    char* sBh  = base + BOFF;
    char* sBl  = sBh + 8192;

    bf16x8 ah[4], al[4], bh[4], bl[4];
    #pragma unroll
    for (int mi = 0; mi < 4; ++mi) {
      int r = wr * 64 + mi * 16 + l15;
      int p = (g ^ (r & 3)) * 16;
      ah[mi] = *(const bf16x8*)(sA + r * 64 + p);
      if (NPROD == 3) al[mi] = *(const bf16x8*)(sAl + r * 64 + p);
    }
    #pragma unroll
    for (int ni = 0; ni < 4; ++ni) {
      int r = wc * 64 + ni * 16 + l15;
      int p = (g ^ (r & 3)) * 16;
      bh[ni] = *(const bf16x8*)(sBh + r * 64 + p);
      if (NPROD == 3) bl[ni] = *(const bf16x8*)(sBl + r * 64 + p);
    }
    __builtin_amdgcn_s_setprio(1);
    #pragma unroll
    for (int mi = 0; mi < 4; ++mi)
      #pragma unroll
      for (int ni = 0; ni < 4; ++ni) {
        acc[mi][ni] = mfma16(ah[mi], bh[ni], acc[mi][ni]);
        if (NPROD == 3) {
          acc[mi][ni] = mfma16(ah[mi], bl[ni], acc[mi][ni]);
          acc[mi][ni] = mfma16(al[mi], bh[ni], acc[mi][ni]);
        }
      }
    __builtin_amdgcn_s_setprio(0);
    __syncthreads();
    cur ^= 1;
  }

  if (MODE == MODE_C) {
    #pragma unroll
    for (int mi = 0; mi < 4; ++mi)
      #pragma unroll
      for (int ni = 0; ni < 4; ++ni) {
        int col = n0 + wc * 64 + ni * 16 + l15;
        #pragma unroll
        for (int r = 0; r < 4; ++r) {
          int row = m0 + wr * 64 + mi * 16 + g * 4 + r;
          C[(size_t)row * DIM + col] = acc[mi][ni][r];
        }
      }
  } else if (MODE == MODE_HILO) {
    #pragma unroll
    for (int mi = 0; mi < 4; ++mi)
      #pragma unroll
      for (int ni = 0; ni < 4; ++ni) {
        int col = n0 + wc * 64 + ni * 16 + l15;
        #pragma unroll
        for (int r = 0; r < 4; ++r) {
          int row = m0 + wr * 64 + mi * 16 + g * 4 + r;
          float v = acc[mi][ni][r] * QSCALE;
          __bf16 h = (__bf16)v;
          Oh[(size_t)row * DIM + col] = h;
          Ol[(size_t)row * DIM + col] = (__bf16)(v - (float)h);
        }
      }
  } else if (MODE == MODE_KV) {
    // Oh = Ktab [b*NPAD+n][64], Ol = VtT [b][64][NPAD] at permuted n'
    #pragma unroll
    for (int mi = 0; mi < 4; ++mi)
      #pragma unroll
      for (int ni = 0; ni < 4; ++ni) {
        int col = wc * 64 + ni * 16 + l15;
        #pragma unroll
        for (int r = 0; r < 4; ++r) {
          int gr = m0 + wr * 64 + mi * 16 + g * 4 + r;
          int bb = gr >> 10, n = gr & (NPAD - 1);
          __bf16 h = (__bf16)acc[mi][ni][r];
          if (col < DHEAD) {
            Oh[(size_t)gr * DHEAD + col] = h;
          } else {
            int np = (n & ~63) | ((n & 15) << 2) | ((n >> 4) & 3);
            Ol[((size_t)bb * DHEAD + (col - DHEAD)) * NPAD + np] = h;
          }
        }
      }
  } else {  // MODE_ARGMAX: per-row TOP-2 over this wave's 64-col half
    #pragma unroll
    for (int mi = 0; mi < 4; ++mi)
      #pragma unroll
      for (int r = 0; r < 4; ++r) {
        float v1 = -FLT_MAX, v2 = -FLT_MAX;
        int   i1 = 0x7fffffff, i2 = 0x7fffffff;
        #pragma unroll
        for (int ni = 0; ni < 4; ++ni) {
          int col = n0 + wc * 64 + ni * 16 + l15;
          float s = (col < NMEM) ? acc[mi][ni][r] : -FLT_MAX;
          if (s > v1 || (s == v1 && col < i1)) { v2 = v1; i2 = i1; v1 = s; i1 = col; }
          else if (s > v2 || (s == v2 && col < i2)) { v2 = s; i2 = col; }
        }
        #pragma unroll
        for (int off = 1; off < 16; off <<= 1) {
          float w1 = __shfl_xor(v1, off), w2 = __shfl_xor(v2, off);
          int   j1 = __shfl_xor(i1, off), j2 = __shfl_xor(i2, off);
          if (w1 > v1 || (w1 == v1 && j1 < i1)) { v2 = v1; i2 = i1; v1 = w1; i1 = j1; }
          else if (w1 > v2 || (w1 == v2 && j1 < i2)) { v2 = w1; i2 = j1; }
          if (w2 > v1 || (w2 == v1 && j2 < i1)) { v2 = v1; i2 = i1; v1 = w2; i1 = j2; }
          else if (w2 > v2 || (w2 == v2 && j2 < i2)) { v2 = w2; i2 = j2; }
        }
        if (l15 == 0) {
          int row = m0 + wr * 64 + mi * 16 + g * 4 + r;
          int half = blockIdx.y * 2 + wc;           // 0..15
          pv[(size_t)(half * 2 + 0) * ROWS + row] = v1;
          pv[(size_t)(half * 2 + 1) * ROWS + row] = v2;
          pi[(size_t)(half * 2 + 0) * ROWS + row] = i1;
          pi[(size_t)(half * 2 + 1) * ROWS + row] = i2;
        }
      }
  }
}

// ---------------------------------------------------------------------------
// Exact rescore (verified round 9).
// ---------------------------------------------------------------------------
__global__ __launch_bounds__(256) void knn_rescore(const __bf16* __restrict__ qph,
                                                   const __bf16* __restrict__ qpl,
                                                   const float* __restrict__ mem,
                                                   const float* __restrict__ pv,
                                                   const int* __restrict__ pi,
                                                   int* __restrict__ idx) {
  const int t = threadIdx.x;
  const int wq = t >> 6, lane = t & 63;
  const int qrow = blockIdx.x * 4 + wq;
  const int batch = qrow >> 11;

  float cv = (lane < 32) ? pv[(size_t)lane * ROWS + qrow] : -FLT_MAX;
  int   ci = (lane < 32) ? pi[(size_t)lane * ROWS + qrow] : 0x7fffffff;

  float M = cv;
  #pragma unroll
  for (int off = 1; off < 64; off <<= 1) M = fmaxf(M, __shfl_xor(M, off));

  unsigned long long cand = __ballot(cv >= M - RESCORE_DELTA && ci < NMEM);

  float qp[16];
  {
    const __bf16* ph = qph + (size_t)qrow * DIM + lane * 16;
    const __bf16* pl = qpl + (size_t)qrow * DIM + lane * 16;
    #pragma unroll
    for (int j = 0; j < 16; ++j) qp[j] = (float)ph[j] + (float)pl[j];
  }

  float best = -FLT_MAX;
  int besti = 0x7fffffff;
  while (cand) {
    int b = __ffsll((long long)cand) - 1;
    cand &= cand - 1;
    int c = __shfl(ci, b);
    const float* mrow = mem + ((size_t)batch * NMEM + c) * DIM + lane * 16;
    float part = 0.f;
    #pragma unroll
    for (int j = 0; j < 16; ++j) part = fmaf(qp[j], mrow[j], part);
    #pragma unroll
    for (int off = 1; off < 64; off <<= 1) part += __shfl_xor(part, off);
    if (part > best || (part == best && c < besti)) { best = part; besti = c; }
  }
  if (lane == 0) idx[qrow] = besti;
}

// ---------------------------------------------------------------------------
// Per-batch histogram of idx -> log2(count) bias (masked slots = -1e30).
// ---------------------------------------------------------------------------
__global__ __launch_bounds__(256) void hist_lc(const int* __restrict__ idx,
                                               float* __restrict__ lc) {
  __shared__ int hcnt[NPAD];
  const int t = threadIdx.x, b = blockIdx.x;
  #pragma unroll
  for (int i = 0; i < 4; ++i) hcnt[t + 256 * i] = 0;
  __syncthreads();
  #pragma unroll
  for (int i = 0; i < 8; ++i) atomicAdd(&hcnt[idx[b * SEQ + i * 256 + t]], 1);
  __syncthreads();
  #pragma unroll
  for (int i = 0; i < 4; ++i) {
    int n = t + 256 * i;
    int c = hcnt[n];
    lc[b * NPAD + n] = (n < NMEM && c > 0) ? log2f((float)c) : -1e30f;
  }
}

// ---------------------------------------------------------------------------
// Attention over the 1000-entry table (verified rounds 12/14): 2 heads/block,
// exp2 softmax, double-buffered K/V, 48 KiB LDS.
// ---------------------------------------------------------------------------
__global__ __launch_bounds__(256, 2) void attn_table(const __bf16* __restrict__ qph,
                                                     const __bf16* __restrict__ Ktab,
                                                     const __bf16* __restrict__ VtTp,
                                                     const float* __restrict__ lc2,
                                                     __bf16* __restrict__ attn_bf) {
  extern __shared__ char smem[];
  char* sK = smem;                 // [2][8192]: K tiles [64 key][64 d]
  char* sV = smem + 16384;         // [2][8192]: V^T tiles [64 d][64 key']
  char* sP = smem + 32768;         // [4 waves][32 rows][64 keys'] (4KB/wave)

  const int t = threadIdx.x;
  const int wq = t >> 6, lane = t & 63, l15 = lane & 15, g = lane >> 4;
  const int b = blockIdx.z, h0 = blockIdx.y * 2;
  const int q0 = blockIdx.x * 128 + wq * 32;

  bf16x8 qa[2][2][2];   // [hh][mi][ks]
  #pragma unroll
  for (int hh = 0; hh < 2; ++hh)
    #pragma unroll
    for (int mi = 0; mi < 2; ++mi)
      #pragma unroll
      for (int ks = 0; ks < 2; ++ks)
        qa[hh][mi][ks] = *(const bf16x8*)&qph[(size_t)(b * SEQ + q0 + mi * 16 + l15) * DIM +
                                              (h0 + hh) * DHEAD + ks * 32 + g * 8];

  f32x4 O[2][2][4];
  #pragma unroll
  for (int hh = 0; hh < 2; ++hh)
    #pragma unroll
    for (int mi = 0; mi < 2; ++mi)
      #pragma unroll
      for (int fd = 0; fd < 4; ++fd) O[hh][mi][fd] = (f32x4){0.f, 0.f, 0.f, 0.f};
  float lsum[2][2][4];
  #pragma unroll
  for (int hh = 0; hh < 2; ++hh)
    #pragma unroll
    for (int mi = 0; mi < 2; ++mi)
      #pragma unroll
      for (int r = 0; r < 4; ++r) lsum[hh][mi][r] = 0.f;

  const __bf16* Kb = Ktab + (size_t)b * NPAD * DHEAD;
  const __bf16* Vb = VtTp + (size_t)b * DHEAD * NPAD;
  const float* lcb = lc2 + b * NPAD;
  char* sPw = sP + wq * 4096;

  auto STAGE = [&](int buf, int tile) {
    const int n0 = tile * 64;
    #pragma unroll
    for (int i = 0; i < 2; ++i) {
      int c = i * 256 + t, row = c >> 3, s = c & 7, sl = s ^ (row & 7);
      GLOAD16(&Kb[(size_t)(n0 + row) * DHEAD + sl * 8], sK + buf * 8192 + i * 4096 + wq * 1024);
      GLOAD16(&Vb[(size_t)row * NPAD + n0 + sl * 8], sV + buf * 8192 + i * 4096 + wq * 1024);
    }
  };

  STAGE(0, 0);
  __syncthreads();
  int cur = 0;

  for (int tile = 0; tile < NPAD / 64; ++tile) {
    if (tile + 1 < NPAD / 64) STAGE(cur ^ 1, tile + 1);

    const int n0 = tile * 64;
    float lcv[4];
    #pragma unroll
    for (int ni = 0; ni < 4; ++ni) lcv[ni] = lcb[n0 + ni * 16 + l15];

    // K fragments once per tile (8 ds_read_b128), shared by both heads
    bf16x8 kf[2][4];
    #pragma unroll
    for (int ks = 0; ks < 2; ++ks)
      #pragma unroll
      for (int ni = 0; ni < 4; ++ni)
        kf[ks][ni] = *(const bf16x8*)(sK + cur * 8192 + (ni * 16 + l15) * 128 +
                                      (((ks * 4 + g) ^ (l15 & 7)) * 16));

    #pragma unroll
    for (int hh = 0; hh < 2; ++hh) {
      // QK + softmax for both mi of this head -> sP (32 rows)
      #pragma unroll
      for (int mi = 0; mi < 2; ++mi) {
        f32x4 S[4];
        #pragma unroll
        for (int ni = 0; ni < 4; ++ni) S[ni] = (f32x4){0.f, 0.f, 0.f, 0.f};
        __builtin_amdgcn_s_setprio(1);
        #pragma unroll
        for (int ks = 0; ks < 2; ++ks)
          #pragma unroll
          for (int ni = 0; ni < 4; ++ni)
            S[ni] = mfma16(qa[hh][mi][ks], kf[ks][ni], S[ni]);
        __builtin_amdgcn_s_setprio(0);
        #pragma unroll
        for (int r = 0; r < 4; ++r) {
          int row = mi * 16 + g * 4 + r;
          bf16x4 p4;
          float rs = 0.f;
          #pragma unroll
          for (int ni = 0; ni < 4; ++ni) {
            float p = __builtin_amdgcn_exp2f(S[ni][r] + lcv[ni]);
            rs += p;
            p4[ni] = (__bf16)p;
          }
          *(bf16x4*)(sPw + row * 128 + ((l15 * 8) ^ ((row & 7) << 4))) = p4;
          lsum[hh][mi][r] += rs;
        }
      }
      // PV for this head: V fragments once per ks, both mi
      #pragma unroll
      for (int ks = 0; ks < 2; ++ks) {
        bf16x8 vf[4];
        #pragma unroll
        for (int fd = 0; fd < 4; ++fd)
          vf[fd] = *(const bf16x8*)(sV + cur * 8192 + (fd * 16 + l15) * 128 +
                                    (((ks * 4 + g) ^ (l15 & 7)) * 16));
        __builtin_amdgcn_s_setprio(1);
        #pragma unroll
        for (int mi = 0; mi < 2; ++mi) {
          int row = mi * 16 + l15;
          bf16x8 pa = *(const bf16x8*)(sPw + row * 128 +
                                       ((ks * 64 + g * 16) ^ ((row & 7) << 4)));
          #pragma unroll
          for (int fd = 0; fd < 4; ++fd)
            O[hh][mi][fd] = mfma16(pa, vf[fd], O[hh][mi][fd]);
        }
        __builtin_amdgcn_s_setprio(0);
      }
    }

    __syncthreads();
    cur ^= 1;
  }

  #pragma unroll
  for (int hh = 0; hh < 2; ++hh)
    #pragma unroll
    for (int mi = 0; mi < 2; ++mi)
      #pragma unroll
      for (int r = 0; r < 4; ++r) {
        float rs = lsum[hh][mi][r];
        #pragma unroll
        for (int off = 1; off < 16; off <<= 1) rs += __shfl_xor(rs, off);
        float inv = 1.f / rs;
        size_t row = (size_t)(b * SEQ + q0 + mi * 16 + g * 4 + r);
        #pragma unroll
        for (int fd = 0; fd < 4; ++fd)
          attn_bf[row * DIM + (h0 + hh) * DHEAD + fd * 16 + l15] =
              (__bf16)(O[hh][mi][fd][r] * inv);
      }
}

// ---------------------------------------------------------------------------
// Fused casts (verified round 15): one launch.
//  blocks [0,256):      w_q transpose -> wqt_h/wqt_l
//  blocks [256,512):    w_concat transpose -> wct
//  blocks [512,544):    w_kv transpose -> wkvT_h/wkvT_l
//  blocks [544,2592):   mem split -> memh/meml (padded)
//  blocks [2592,6688):  q split -> qh/ql
// ---------------------------------------------------------------------------
__global__ __launch_bounds__(256) void cast_all(const float* __restrict__ w_q,
                                                const float* __restrict__ w_concat,
                                                const float* __restrict__ w_kv,
                                                const float* __restrict__ mem,
                                                const float* __restrict__ q,
                                                __bf16* __restrict__ wqt_h,
                                                __bf16* __restrict__ wqt_l,
                                                __bf16* __restrict__ wct,
                                                __bf16* __restrict__ wkvT_h,
                                                __bf16* __restrict__ wkvT_l,
                                                __bf16* __restrict__ mh,
                                                __bf16* __restrict__ ml,
                                                __bf16* __restrict__ qh,
                                                __bf16* __restrict__ ql) {
  __shared__ float tile[64][65];
  const int t = threadIdx.x;
  const int id = blockIdx.x;
  if (id < 544) {
    const float* src;
    __bf16 *oh, *ol;
    int kt, nt, srcStride, writeLo;
    if (id < 256)      { src = w_q;      oh = wqt_h;  ol = wqt_l;  kt = id & 15;         nt = id >> 4;         srcStride = DIM; writeLo = 1; }
    else if (id < 512) { src = w_concat; oh = wct;    ol = 0;      kt = (id - 256) & 15; nt = (id - 256) >> 4; srcStride = DIM; writeLo = 0; }
    else               { src = w_kv;     oh = wkvT_h; ol = wkvT_l; kt = (id - 512) & 15; nt = (id - 512) >> 4; srcStride = 128; writeLo = 1; }
    const int k0 = kt * 64, n0 = nt * 64;
    #pragma unroll
    for (int i = 0; i < 16; ++i) {
      int e = t + i * 256, r = e >> 6, c = e & 63;
      tile[r][c] = src[(size_t)(k0 + r) * srcStride + n0 + c];
    }
    __syncthreads();
    #pragma unroll
    for (int i = 0; i < 16; ++i) {
      int e = t + i * 256, r = e >> 6, c = e & 63;
      float v = tile[c][r];
      __bf16 h = (__bf16)v;
      oh[(size_t)(n0 + r) * DIM + k0 + c] = h;
      if (writeLo) ol[(size_t)(n0 + r) * DIM + k0 + c] = (__bf16)(v - (float)h);
    }
  } else if (id < 2592) {
    size_t e = ((size_t)(id - 544) * 256 + t) * 8;
    int d = (int)(e & 1023);
    size_t rn = e >> 10;
    int n = (int)(rn & 1023), b = (int)(rn >> 10);
    bf16x8 h8, l8;
    if (n < NMEM) {
      const float* p = mem + ((size_t)b * NMEM + n) * DIM + d;
      #pragma unroll
      for (int j = 0; j < 8; ++j) {
        float v = p[j];
        __bf16 h = (__bf16)v;
        h8[j] = h; l8[j] = (__bf16)(v - (float)h);
      }
    } else {
      #pragma unroll
      for (int j = 0; j < 8; ++j) { h8[j] = (__bf16)0.f; l8[j] = (__bf16)0.f; }
    }
    *(bf16x8*)(mh + e) = h8;
    *(bf16x8*)(ml + e) = l8;
  } else {
    size_t e = ((size_t)(id - 2592) * 256 + t) * 8;
    float4 a = *(const float4*)(q + e);
    float4 bq = *(const float4*)(q + e + 4);
    float vv[8] = {a.x, a.y, a.z, a.w, bq.x, bq.y, bq.z, bq.w};
    bf16x8 h8, l8;
    #pragma unroll
    for (int j = 0; j < 8; ++j) {
      __bf16 h = (__bf16)vv[j];
      h8[j] = h; l8[j] = (__bf16)(vv[j] - (float)h);
    }
    *(bf16x8*)(qh + e) = h8;
    *(bf16x8*)(ql + e) = l8;
  }
}

// ---------------------------------------------------------------------------
extern "C" void kernel_launch(void* const* d_in, const int* in_sizes, int n_in,
                              void* d_out, int out_size, void* d_ws, size_t ws_size,
                              hipStream_t stream) {
  const float* q        = (const float*)d_in[0];
  const float* mem      = (const float*)d_in[2];
  const float* w_q      = (const float*)d_in[3];
  const float* w_kv     = (const float*)d_in[4];
  const float* w_concat = (const float*)d_in[5];
  float* out = (float*)d_out;

  char* wsb = (char*)d_ws;
  __bf16* memh   = (__bf16*)(wsb + 0);                  //  8 MiB
  __bf16* meml   = (__bf16*)(wsb + 8388608);            //  8 MiB
  __bf16* wqt_h  = (__bf16*)(wsb + 16777216);           //  2 MiB
  __bf16* wqt_l  = (__bf16*)(wsb + 18874368);           //  2 MiB
  __bf16* wct    = (__bf16*)(wsb + 20971520);           //  2 MiB
  __bf16* Ktab   = (__bf16*)(wsb + 23068672);           //  512 KiB
  __bf16* VtT    = (__bf16*)(wsb + 23592960);           //  512 KiB
  float*  lc     = (float*) (wsb + 24117248);           //  16 KiB
  float*  pv     = (float*) (wsb + 24133632);           //  1 MiB  [32][8192]
  int*    pi     = (int*)   (wsb + 25182208);           //  1 MiB  [32][8192]
  int*    idx    = (int*)   (wsb + 26230784);           //  32 KiB
  __bf16* wkvT_h = (__bf16*)(wsb + 26263552);           //  256 KiB
  __bf16* wkvT_l = (__bf16*)(wsb + 26525696);           //  256 KiB
  __bf16* qph    = (__bf16*)(wsb + 26787840);           // 16 MiB
  __bf16* qpl    = (__bf16*)(wsb + 43565056);           // 16 MiB (reused as attn_bf)
  __bf16* attn_bf = qpl;
  // q hi/lo parked in d_out (32 MiB, dead until the final GEMM writes it)
  __bf16* qh = (__bf16*)d_out;
  __bf16* ql = (__bf16*)d_out + (size_t)ROWS * DIM;

  // 1. all casts in one launch
  cast_all<<<dim3(6688), 256, 0, stream>>>(w_q, w_concat, w_kv, mem, q,
                                           wqt_h, wqt_l, wct, wkvT_h, wkvT_l,
                                           memh, meml, qh, ql);

  // 2. qp = q @ w_q (pre-split A, 3-product), QSCALE-scaled -> qph/qpl
  gemm3<3, MODE_HILO><<<dim3(64, 8, 1), 256, 65536, stream>>>(
      qh, ql, wqt_h, wqt_l, 0, 0,
      (float*)0, qph, qpl, (float*)0, (int*)0);

  // 3. K/V tables: (memh/meml) @ w_kv^T -> Ktab, VtT (permuted)
  gemm3<3, MODE_KV><<<dim3(BATCH * NPAD / 128, 1, 1), 256, 65536, stream>>>(
      memh, meml, wkvT_h, wkvT_l, 0, 0,
      (float*)0, Ktab, VtT, (float*)0, (int*)0);

  // 4. approx scores (1-product) + top-2-per-half candidates
  gemm3<1, MODE_ARGMAX><<<dim3(16, 8, 4), 256, 32768, stream>>>(
      qph, (const __bf16*)0, memh, (const __bf16*)0, 2048, (long)NPAD * DIM,
      (float*)0, (__bf16*)0, (__bf16*)0, pv, pi);

  // 5. exact rescore of candidates -> exact argmax
  knn_rescore<<<dim3(ROWS / 4), 256, 0, stream>>>(qph, qpl, mem, pv, pi, idx);

  // 6. counts -> log2 bias
  hist_lc<<<dim3(BATCH), 256, 0, stream>>>(idx, lc);

  // 7. attention over the table (2 heads/block, 48 KiB LDS)
  attn_table<<<dim3(SEQ / 128, NHEAD / 2, BATCH), 256, 49152, stream>>>(
      qph, Ktab, VtT, lc, attn_bf);

  // 8. out = attn @ w_concat (overwrites the qh/ql scratch in d_out)
  gemm3<1, MODE_C><<<dim3(64, 8, 1), 256, 32768, stream>>>(
      attn_bf, (const __bf16*)0, wct, (const __bf16*)0, 0, 0,
      out, (__bf16*)0, (__bf16*)0, (float*)0, (int*)0);
}

// Round 17
// 221.053 us; speedup vs baseline: 1.0254x; 1.0254x over previous
//
#include <hip/hip_runtime.h>
#include <float.h>
#include <math.h>

// KNNAttention: b=4, l=2048, d=1024, h=16, dh=64, n_mem=1000
#define BATCH 4
#define SEQ   2048
#define DIM   1024
#define NHEAD 16
#define DHEAD 64
#define NMEM  1000
#define NPAD  1024          // padded memory slots
#define ROWS  (BATCH*SEQ)   // 8192
// qp pre-scale: 0.125 * log2(e); softmax becomes exp2(S + log2(count))
#define QSCALE 0.18033688011112042f
// rescore window (scaled-score units): ~7.4 sigma of 1-product score noise
#define RESCORE_DELTA 0.10f

typedef __attribute__((ext_vector_type(8))) __bf16 bf16x8;
typedef __attribute__((ext_vector_type(4))) __bf16 bf16x4;
typedef __attribute__((ext_vector_type(4))) float  f32x4;

static __device__ inline f32x4 mfma16(bf16x8 a, bf16x8 b, f32x4 c) {
  return __builtin_amdgcn_mfma_f32_16x16x32_bf16(a, b, c, 0, 0, 0);
}

// async global->LDS, 16B per lane. LDS dest must be wave-uniform base (+lane*16).
#define GLOAD16(g, l) __builtin_amdgcn_global_load_lds( \
    (const __attribute__((address_space(1))) unsigned int*)(g), \
    (__attribute__((address_space(3))) unsigned int*)(l), 16, 0, 0)

enum { MODE_C = 0, MODE_HILO = 1, MODE_ARGMAX = 2, MODE_KV = 3, MODE_QPKV = 4 };

// ---------------------------------------------------------------------------
// Fused split-bf16 GEMM (bodies verified rounds 2-14): C = A * B^T, up to 3
// products (Ah*Bh + Ah*Bl + Al*Bh). Double-buffered staging.
// MODE_QPKV (verified round 15, wall-best): one launch runs BOTH the qp-HILO
// GEMM (blocks bx<64, 512 blocks) and the K/V-table GEMM (bx>=64, 32 blocks;
// A2*/B2* pointers, KV epilogue) — KV rides the CU wavefront of qp's tail and
// one graph node disappears. (A/B rounds 15/16: fused 222 vs split 227 µs.)
// MODE_ARGMAX (NPROD=1): per-row TOP-2 per 64-col half -> pv/pi[32][ROWS].
// ---------------------------------------------------------------------------
template<int NPROD, int MODE>
__global__ __launch_bounds__(256) void gemm3(
    const __bf16* __restrict__ Ah, const __bf16* __restrict__ Al,
    const __bf16* __restrict__ Bh, const __bf16* __restrict__ Bl,
    int rowsPerZ, long bStrideZ,
    float* __restrict__ C, __bf16* __restrict__ Oh, __bf16* __restrict__ Ol,
    float* __restrict__ pv, int* __restrict__ pi,
    const __bf16* __restrict__ A2h, const __bf16* __restrict__ A2l,
    const __bf16* __restrict__ B2h, const __bf16* __restrict__ B2l,
    __bf16* __restrict__ Ktab, __bf16* __restrict__ VtT)
{
  extern __shared__ char smem[];
  const int t = threadIdx.x;
  const int w = t >> 6, lane = t & 63, l15 = lane & 15, g = lane >> 4;
  const int wr = w >> 1, wc = w & 1;

  int m0, n0;
  bool kvPath = false;
  const __bf16 *pAh, *pAl, *pBh, *pBl;
  if constexpr (MODE == MODE_QPKV) {
    if (blockIdx.x >= 64) {
      int k = (blockIdx.x - 64) * 8 + blockIdx.y;
      if (k >= 32) return;                     // 32 idle filler blocks
      kvPath = true;
      m0 = k * 128; n0 = 0;
      pAh = A2h; pAl = A2l; pBh = B2h; pBl = B2l;
    } else {
      m0 = blockIdx.x * 128; n0 = blockIdx.y * 128;
      pAh = Ah; pAl = Al; pBh = Bh; pBl = Bl;
    }
  } else {
    m0 = blockIdx.z * rowsPerZ + blockIdx.x * 128;
    n0 = blockIdx.y * 128;
    pAh = Ah; pAl = Al;
    pBh = Bh + (size_t)blockIdx.z * bStrideZ;
    pBl = (NPROD == 3) ? (Bl + (size_t)blockIdx.z * bStrideZ) : (const __bf16*)0;
  }

  constexpr int SB   = (NPROD == 3) ? 32768 : 16384;
  constexpr int BOFF = (NPROD == 3) ? 16384 : 8192;

  f32x4 acc[4][4];
  #pragma unroll
  for (int i = 0; i < 4; ++i)
    #pragma unroll
    for (int j = 0; j < 4; ++j) acc[i][j] = (f32x4){0.f, 0.f, 0.f, 0.f};

  auto STAGE = [&](int buf, int k0) {
    char* base = smem + buf * SB;
    #pragma unroll
    for (int i = 0; i < 2; ++i) {
      int c = i * 256 + t;
      int r = c >> 2, s = c & 3;
      int sl = s ^ (r & 3);
      GLOAD16(&pAh[(size_t)(m0 + r) * DIM + k0 + sl * 8], base + i * 4096 + w * 1024);
      if (NPROD == 3)
        GLOAD16(&pAl[(size_t)(m0 + r) * DIM + k0 + sl * 8], base + 8192 + i * 4096 + w * 1024);
    }
    char* bB = base + BOFF;
    #pragma unroll
    for (int i = 0; i < 2; ++i) {
      int c = i * 256 + t;
      int r = c >> 2, s = c & 3;
      int sl = s ^ (r & 3);
      GLOAD16(&pBh[(size_t)(n0 + r) * DIM + k0 + sl * 8], bB + i * 4096 + w * 1024);
      if (NPROD == 3)
        GLOAD16(&pBl[(size_t)(n0 + r) * DIM + k0 + sl * 8], bB + 8192 + i * 4096 + w * 1024);
    }
  };

  STAGE(0, 0);
  __syncthreads();
  int cur = 0;

  for (int k0 = 0; k0 < DIM; k0 += 32) {
    if (k0 + 32 < DIM) STAGE(cur ^ 1, k0 + 32);   // prefetch next tile

    char* base = smem + cur * SB;
    char* sA   = base;
    char* sAl  = base + 8192;
    char* sBh  = base + BOFF;
    char* sBl  = sBh + 8192;

    bf16x8 ah[4], al[4], bh[4], bl[4];
    #pragma unroll
    for (int mi = 0; mi < 4; ++mi) {
      int r = wr * 64 + mi * 16 + l15;
      int p = (g ^ (r & 3)) * 16;
      ah[mi] = *(const bf16x8*)(sA + r * 64 + p);
      if (NPROD == 3) al[mi] = *(const bf16x8*)(sAl + r * 64 + p);
    }
    #pragma unroll
    for (int ni = 0; ni < 4; ++ni) {
      int r = wc * 64 + ni * 16 + l15;
      int p = (g ^ (r & 3)) * 16;
      bh[ni] = *(const bf16x8*)(sBh + r * 64 + p);
      if (NPROD == 3) bl[ni] = *(const bf16x8*)(sBl + r * 64 + p);
    }
    __builtin_amdgcn_s_setprio(1);
    #pragma unroll
    for (int mi = 0; mi < 4; ++mi)
      #pragma unroll
      for (int ni = 0; ni < 4; ++ni) {
        acc[mi][ni] = mfma16(ah[mi], bh[ni], acc[mi][ni]);
        if (NPROD == 3) {
          acc[mi][ni] = mfma16(ah[mi], bl[ni], acc[mi][ni]);
          acc[mi][ni] = mfma16(al[mi], bh[ni], acc[mi][ni]);
        }
      }
    __builtin_amdgcn_s_setprio(0);
    __syncthreads();
    cur ^= 1;
  }

  if (MODE == MODE_C) {
    #pragma unroll
    for (int mi = 0; mi < 4; ++mi)
      #pragma unroll
      for (int ni = 0; ni < 4; ++ni) {
        int col = n0 + wc * 64 + ni * 16 + l15;
        #pragma unroll
        for (int r = 0; r < 4; ++r) {
          int row = m0 + wr * 64 + mi * 16 + g * 4 + r;
          C[(size_t)row * DIM + col] = acc[mi][ni][r];
        }
      }
  } else if (MODE == MODE_QPKV) {
    if (!kvPath) {   // HILO epilogue: qph/qpl, QSCALE-scaled
      #pragma unroll
      for (int mi = 0; mi < 4; ++mi)
        #pragma unroll
        for (int ni = 0; ni < 4; ++ni) {
          int col = n0 + wc * 64 + ni * 16 + l15;
          #pragma unroll
          for (int r = 0; r < 4; ++r) {
            int row = m0 + wr * 64 + mi * 16 + g * 4 + r;
            float v = acc[mi][ni][r] * QSCALE;
            __bf16 h = (__bf16)v;
            Oh[(size_t)row * DIM + col] = h;
            Ol[(size_t)row * DIM + col] = (__bf16)(v - (float)h);
          }
        }
    } else {         // KV epilogue: Ktab row-major + VtT transposed/permuted
      #pragma unroll
      for (int mi = 0; mi < 4; ++mi)
        #pragma unroll
        for (int ni = 0; ni < 4; ++ni) {
          int col = wc * 64 + ni * 16 + l15;
          #pragma unroll
          for (int r = 0; r < 4; ++r) {
            int gr = m0 + wr * 64 + mi * 16 + g * 4 + r;
            int bb = gr >> 10, n = gr & (NPAD - 1);
            __bf16 h = (__bf16)acc[mi][ni][r];
            if (col < DHEAD) {
              Ktab[(size_t)gr * DHEAD + col] = h;
            } else {
              int np = (n & ~63) | ((n & 15) << 2) | ((n >> 4) & 3);
              VtT[((size_t)bb * DHEAD + (col - DHEAD)) * NPAD + np] = h;
            }
          }
        }
    }
  } else {  // MODE_ARGMAX: per-row TOP-2 over this wave's 64-col half
    #pragma unroll
    for (int mi = 0; mi < 4; ++mi)
      #pragma unroll
      for (int r = 0; r < 4; ++r) {
        float v1 = -FLT_MAX, v2 = -FLT_MAX;
        int   i1 = 0x7fffffff, i2 = 0x7fffffff;
        #pragma unroll
        for (int ni = 0; ni < 4; ++ni) {
          int col = n0 + wc * 64 + ni * 16 + l15;
          float s = (col < NMEM) ? acc[mi][ni][r] : -FLT_MAX;
          if (s > v1 || (s == v1 && col < i1)) { v2 = v1; i2 = i1; v1 = s; i1 = col; }
          else if (s > v2 || (s == v2 && col < i2)) { v2 = s; i2 = col; }
        }
        #pragma unroll
        for (int off = 1; off < 16; off <<= 1) {
          float w1 = __shfl_xor(v1, off), w2 = __shfl_xor(v2, off);
          int   j1 = __shfl_xor(i1, off), j2 = __shfl_xor(i2, off);
          if (w1 > v1 || (w1 == v1 && j1 < i1)) { v2 = v1; i2 = i1; v1 = w1; i1 = j1; }
          else if (w1 > v2 || (w1 == v2 && j1 < i2)) { v2 = w1; i2 = j1; }
          if (w2 > v1 || (w2 == v1 && j2 < i1)) { v2 = v1; i2 = i1; v1 = w2; i1 = j2; }
          else if (w2 > v2 || (w2 == v2 && j2 < i2)) { v2 = w2; i2 = j2; }
        }
        if (l15 == 0) {
          int row = m0 + wr * 64 + mi * 16 + g * 4 + r;
          int half = blockIdx.y * 2 + wc;           // 0..15
          pv[(size_t)(half * 2 + 0) * ROWS + row] = v1;
          pv[(size_t)(half * 2 + 1) * ROWS + row] = v2;
          pi[(size_t)(half * 2 + 0) * ROWS + row] = i1;
          pi[(size_t)(half * 2 + 1) * ROWS + row] = i2;
        }
      }
  }
}

// ---------------------------------------------------------------------------
// Exact rescore (verified round 9).
// ---------------------------------------------------------------------------
__global__ __launch_bounds__(256) void knn_rescore(const __bf16* __restrict__ qph,
                                                   const __bf16* __restrict__ qpl,
                                                   const float* __restrict__ mem,
                                                   const float* __restrict__ pv,
                                                   const int* __restrict__ pi,
                                                   int* __restrict__ idx) {
  const int t = threadIdx.x;
  const int wq = t >> 6, lane = t & 63;
  const int qrow = blockIdx.x * 4 + wq;
  const int batch = qrow >> 11;

  float cv = (lane < 32) ? pv[(size_t)lane * ROWS + qrow] : -FLT_MAX;
  int   ci = (lane < 32) ? pi[(size_t)lane * ROWS + qrow] : 0x7fffffff;

  float M = cv;
  #pragma unroll
  for (int off = 1; off < 64; off <<= 1) M = fmaxf(M, __shfl_xor(M, off));

  unsigned long long cand = __ballot(cv >= M - RESCORE_DELTA && ci < NMEM);

  float qp[16];
  {
    const __bf16* ph = qph + (size_t)qrow * DIM + lane * 16;
    const __bf16* pl = qpl + (size_t)qrow * DIM + lane * 16;
    #pragma unroll
    for (int j = 0; j < 16; ++j) qp[j] = (float)ph[j] + (float)pl[j];
  }

  float best = -FLT_MAX;
  int besti = 0x7fffffff;
  while (cand) {
    int b = __ffsll((long long)cand) - 1;
    cand &= cand - 1;
    int c = __shfl(ci, b);
    const float* mrow = mem + ((size_t)batch * NMEM + c) * DIM + lane * 16;
    float part = 0.f;
    #pragma unroll
    for (int j = 0; j < 16; ++j) part = fmaf(qp[j], mrow[j], part);
    #pragma unroll
    for (int off = 1; off < 64; off <<= 1) part += __shfl_xor(part, off);
    if (part > best || (part == best && c < besti)) { best = part; besti = c; }
  }
  if (lane == 0) idx[qrow] = besti;
}

// ---------------------------------------------------------------------------
// Per-batch histogram of idx -> log2(count) bias (masked slots = -1e30).
// ---------------------------------------------------------------------------
__global__ __launch_bounds__(256) void hist_lc(const int* __restrict__ idx,
                                               float* __restrict__ lc) {
  __shared__ int hcnt[NPAD];
  const int t = threadIdx.x, b = blockIdx.x;
  #pragma unroll
  for (int i = 0; i < 4; ++i) hcnt[t + 256 * i] = 0;
  __syncthreads();
  #pragma unroll
  for (int i = 0; i < 8; ++i) atomicAdd(&hcnt[idx[b * SEQ + i * 256 + t]], 1);
  __syncthreads();
  #pragma unroll
  for (int i = 0; i < 4; ++i) {
    int n = t + 256 * i;
    int c = hcnt[n];
    lc[b * NPAD + n] = (n < NMEM && c > 0) ? log2f((float)c) : -1e30f;
  }
}

// ---------------------------------------------------------------------------
// Attention over the 1000-entry table (verified rounds 12/14/15):
// 2 heads/block, exp2 softmax, double-buffered K/V, 48 KiB LDS.
// ---------------------------------------------------------------------------
__global__ __launch_bounds__(256, 2) void attn_table(const __bf16* __restrict__ qph,
                                                     const __bf16* __restrict__ Ktab,
                                                     const __bf16* __restrict__ VtTp,
                                                     const float* __restrict__ lc2,
                                                     __bf16* __restrict__ attn_bf) {
  extern __shared__ char smem[];
  char* sK = smem;                 // [2][8192]: K tiles [64 key][64 d]
  char* sV = smem + 16384;         // [2][8192]: V^T tiles [64 d][64 key']
  char* sP = smem + 32768;         // [4 waves][32 rows][64 keys'] (4KB/wave)

  const int t = threadIdx.x;
  const int wq = t >> 6, lane = t & 63, l15 = lane & 15, g = lane >> 4;
  const int b = blockIdx.z, h0 = blockIdx.y * 2;
  const int q0 = blockIdx.x * 128 + wq * 32;

  bf16x8 qa[2][2][2];   // [hh][mi][ks]
  #pragma unroll
  for (int hh = 0; hh < 2; ++hh)
    #pragma unroll
    for (int mi = 0; mi < 2; ++mi)
      #pragma unroll
      for (int ks = 0; ks < 2; ++ks)
        qa[hh][mi][ks] = *(const bf16x8*)&qph[(size_t)(b * SEQ + q0 + mi * 16 + l15) * DIM +
                                              (h0 + hh) * DHEAD + ks * 32 + g * 8];

  f32x4 O[2][2][4];
  #pragma unroll
  for (int hh = 0; hh < 2; ++hh)
    #pragma unroll
    for (int mi = 0; mi < 2; ++mi)
      #pragma unroll
      for (int fd = 0; fd < 4; ++fd) O[hh][mi][fd] = (f32x4){0.f, 0.f, 0.f, 0.f};
  float lsum[2][2][4];
  #pragma unroll
  for (int hh = 0; hh < 2; ++hh)
    #pragma unroll
    for (int mi = 0; mi < 2; ++mi)
      #pragma unroll
      for (int r = 0; r < 4; ++r) lsum[hh][mi][r] = 0.f;

  const __bf16* Kb = Ktab + (size_t)b * NPAD * DHEAD;
  const __bf16* Vb = VtTp + (size_t)b * DHEAD * NPAD;
  const float* lcb = lc2 + b * NPAD;
  char* sPw = sP + wq * 4096;

  auto STAGE = [&](int buf, int tile) {
    const int n0 = tile * 64;
    #pragma unroll
    for (int i = 0; i < 2; ++i) {
      int c = i * 256 + t, row = c >> 3, s = c & 7, sl = s ^ (row & 7);
      GLOAD16(&Kb[(size_t)(n0 + row) * DHEAD + sl * 8], sK + buf * 8192 + i * 4096 + wq * 1024);
      GLOAD16(&Vb[(size_t)row * NPAD + n0 + sl * 8], sV + buf * 8192 + i * 4096 + wq * 1024);
    }
  };

  STAGE(0, 0);
  __syncthreads();
  int cur = 0;

  for (int tile = 0; tile < NPAD / 64; ++tile) {
    if (tile + 1 < NPAD / 64) STAGE(cur ^ 1, tile + 1);

    const int n0 = tile * 64;
    float lcv[4];
    #pragma unroll
    for (int ni = 0; ni < 4; ++ni) lcv[ni] = lcb[n0 + ni * 16 + l15];

    // K fragments once per tile (8 ds_read_b128), shared by both heads
    bf16x8 kf[2][4];
    #pragma unroll
    for (int ks = 0; ks < 2; ++ks)
      #pragma unroll
      for (int ni = 0; ni < 4; ++ni)
        kf[ks][ni] = *(const bf16x8*)(sK + cur * 8192 + (ni * 16 + l15) * 128 +
                                      (((ks * 4 + g) ^ (l15 & 7)) * 16));

    #pragma unroll
    for (int hh = 0; hh < 2; ++hh) {
      // QK + softmax for both mi of this head -> sP (32 rows)
      #pragma unroll
      for (int mi = 0; mi < 2; ++mi) {
        f32x4 S[4];
        #pragma unroll
        for (int ni = 0; ni < 4; ++ni) S[ni] = (f32x4){0.f, 0.f, 0.f, 0.f};
        __builtin_amdgcn_s_setprio(1);
        #pragma unroll
        for (int ks = 0; ks < 2; ++ks)
          #pragma unroll
          for (int ni = 0; ni < 4; ++ni)
            S[ni] = mfma16(qa[hh][mi][ks], kf[ks][ni], S[ni]);
        __builtin_amdgcn_s_setprio(0);
        #pragma unroll
        for (int r = 0; r < 4; ++r) {
          int row = mi * 16 + g * 4 + r;
          bf16x4 p4;
          float rs = 0.f;
          #pragma unroll
          for (int ni = 0; ni < 4; ++ni) {
            float p = __builtin_amdgcn_exp2f(S[ni][r] + lcv[ni]);
            rs += p;
            p4[ni] = (__bf16)p;
          }
          *(bf16x4*)(sPw + row * 128 + ((l15 * 8) ^ ((row & 7) << 4))) = p4;
          lsum[hh][mi][r] += rs;
        }
      }
      // PV for this head: V fragments once per ks, both mi
      #pragma unroll
      for (int ks = 0; ks < 2; ++ks) {
        bf16x8 vf[4];
        #pragma unroll
        for (int fd = 0; fd < 4; ++fd)
          vf[fd] = *(const bf16x8*)(sV + cur * 8192 + (fd * 16 + l15) * 128 +
                                    (((ks * 4 + g) ^ (l15 & 7)) * 16));
        __builtin_amdgcn_s_setprio(1);
        #pragma unroll
        for (int mi = 0; mi < 2; ++mi) {
          int row = mi * 16 + l15;
          bf16x8 pa = *(const bf16x8*)(sPw + row * 128 +
                                       ((ks * 64 + g * 16) ^ ((row & 7) << 4)));
          #pragma unroll
          for (int fd = 0; fd < 4; ++fd)
            O[hh][mi][fd] = mfma16(pa, vf[fd], O[hh][mi][fd]);
        }
        __builtin_amdgcn_s_setprio(0);
      }
    }

    __syncthreads();
    cur ^= 1;
  }

  #pragma unroll
  for (int hh = 0; hh < 2; ++hh)
    #pragma unroll
    for (int mi = 0; mi < 2; ++mi)
      #pragma unroll
      for (int r = 0; r < 4; ++r) {
        float rs = lsum[hh][mi][r];
        #pragma unroll
        for (int off = 1; off < 16; off <<= 1) rs += __shfl_xor(rs, off);
        float inv = 1.f / rs;
        size_t row = (size_t)(b * SEQ + q0 + mi * 16 + g * 4 + r);
        #pragma unroll
        for (int fd = 0; fd < 4; ++fd)
          attn_bf[row * DIM + (h0 + hh) * DHEAD + fd * 16 + l15] =
              (__bf16)(O[hh][mi][fd][r] * inv);
      }
}

// ---------------------------------------------------------------------------
// Fused casts (verified round 15): one launch.
//  blocks [0,256):      w_q transpose -> wqt_h/wqt_l
//  blocks [256,512):    w_concat transpose -> wct
//  blocks [512,544):    w_kv transpose -> wkvT_h/wkvT_l
//  blocks [544,2592):   mem split -> memh/meml (padded)
//  blocks [2592,6688):  q split -> qh/ql
// ---------------------------------------------------------------------------
__global__ __launch_bounds__(256) void cast_all(const float* __restrict__ w_q,
                                                const float* __restrict__ w_concat,
                                                const float* __restrict__ w_kv,
                                                const float* __restrict__ mem,
                                                const float* __restrict__ q,
                                                __bf16* __restrict__ wqt_h,
                                                __bf16* __restrict__ wqt_l,
                                                __bf16* __restrict__ wct,
                                                __bf16* __restrict__ wkvT_h,
                                                __bf16* __restrict__ wkvT_l,
                                                __bf16* __restrict__ mh,
                                                __bf16* __restrict__ ml,
                                                __bf16* __restrict__ qh,
                                                __bf16* __restrict__ ql) {
  __shared__ float tile[64][65];
  const int t = threadIdx.x;
  const int id = blockIdx.x;
  if (id < 544) {
    const float* src;
    __bf16 *oh, *ol;
    int kt, nt, srcStride, writeLo;
    if (id < 256)      { src = w_q;      oh = wqt_h;  ol = wqt_l;  kt = id & 15;         nt = id >> 4;         srcStride = DIM; writeLo = 1; }
    else if (id < 512) { src = w_concat; oh = wct;    ol = 0;      kt = (id - 256) & 15; nt = (id - 256) >> 4; srcStride = DIM; writeLo = 0; }
    else               { src = w_kv;     oh = wkvT_h; ol = wkvT_l; kt = (id - 512) & 15; nt = (id - 512) >> 4; srcStride = 128; writeLo = 1; }
    const int k0 = kt * 64, n0 = nt * 64;
    #pragma unroll
    for (int i = 0; i < 16; ++i) {
      int e = t + i * 256, r = e >> 6, c = e & 63;
      tile[r][c] = src[(size_t)(k0 + r) * srcStride + n0 + c];
    }
    __syncthreads();
    #pragma unroll
    for (int i = 0; i < 16; ++i) {
      int e = t + i * 256, r = e >> 6, c = e & 63;
      float v = tile[c][r];
      __bf16 h = (__bf16)v;
      oh[(size_t)(n0 + r) * DIM + k0 + c] = h;
      if (writeLo) ol[(size_t)(n0 + r) * DIM + k0 + c] = (__bf16)(v - (float)h);
    }
  } else if (id < 2592) {
    size_t e = ((size_t)(id - 544) * 256 + t) * 8;
    int d = (int)(e & 1023);
    size_t rn = e >> 10;
    int n = (int)(rn & 1023), b = (int)(rn >> 10);
    bf16x8 h8, l8;
    if (n < NMEM) {
      const float* p = mem + ((size_t)b * NMEM + n) * DIM + d;
      #pragma unroll
      for (int j = 0; j < 8; ++j) {
        float v = p[j];
        __bf16 h = (__bf16)v;
        h8[j] = h; l8[j] = (__bf16)(v - (float)h);
      }
    } else {
      #pragma unroll
      for (int j = 0; j < 8; ++j) { h8[j] = (__bf16)0.f; l8[j] = (__bf16)0.f; }
    }
    *(bf16x8*)(mh + e) = h8;
    *(bf16x8*)(ml + e) = l8;
  } else {
    size_t e = ((size_t)(id - 2592) * 256 + t) * 8;
    float4 a = *(const float4*)(q + e);
    float4 bq = *(const float4*)(q + e + 4);
    float vv[8] = {a.x, a.y, a.z, a.w, bq.x, bq.y, bq.z, bq.w};
    bf16x8 h8, l8;
    #pragma unroll
    for (int j = 0; j < 8; ++j) {
      __bf16 h = (__bf16)vv[j];
      h8[j] = h; l8[j] = (__bf16)(vv[j] - (float)h);
    }
    *(bf16x8*)(qh + e) = h8;
    *(bf16x8*)(ql + e) = l8;
  }
}

// ---------------------------------------------------------------------------
extern "C" void kernel_launch(void* const* d_in, const int* in_sizes, int n_in,
                              void* d_out, int out_size, void* d_ws, size_t ws_size,
                              hipStream_t stream) {
  const float* q        = (const float*)d_in[0];
  const float* mem      = (const float*)d_in[2];
  const float* w_q      = (const float*)d_in[3];
  const float* w_kv     = (const float*)d_in[4];
  const float* w_concat = (const float*)d_in[5];
  float* out = (float*)d_out;

  char* wsb = (char*)d_ws;
  __bf16* memh   = (__bf16*)(wsb + 0);                  //  8 MiB
  __bf16* meml   = (__bf16*)(wsb + 8388608);            //  8 MiB
  __bf16* wqt_h  = (__bf16*)(wsb + 16777216);           //  2 MiB
  __bf16* wqt_l  = (__bf16*)(wsb + 18874368);           //  2 MiB
  __bf16* wct    = (__bf16*)(wsb + 20971520);           //  2 MiB
  __bf16* Ktab   = (__bf16*)(wsb + 23068672);           //  512 KiB
  __bf16* VtT    = (__bf16*)(wsb + 23592960);           //  512 KiB
  float*  lc     = (float*) (wsb + 24117248);           //  16 KiB
  float*  pv     = (float*) (wsb + 24133632);           //  1 MiB  [32][8192]
  int*    pi     = (int*)   (wsb + 25182208);           //  1 MiB  [32][8192]
  int*    idx    = (int*)   (wsb + 26230784);           //  32 KiB
  __bf16* wkvT_h = (__bf16*)(wsb + 26263552);           //  256 KiB
  __bf16* wkvT_l = (__bf16*)(wsb + 26525696);           //  256 KiB
  __bf16* qph    = (__bf16*)(wsb + 26787840);           // 16 MiB
  __bf16* qpl    = (__bf16*)(wsb + 43565056);           // 16 MiB (reused as attn_bf)
  __bf16* attn_bf = qpl;
  // q hi/lo parked in d_out (32 MiB, dead until the final GEMM writes it)
  __bf16* qh = (__bf16*)d_out;
  __bf16* ql = (__bf16*)d_out + (size_t)ROWS * DIM;

  // 1. all casts in one launch
  cast_all<<<dim3(6688), 256, 0, stream>>>(w_q, w_concat, w_kv, mem, q,
                                           wqt_h, wqt_l, wct, wkvT_h, wkvT_l,
                                           memh, meml, qh, ql);

  // 2. fused: qp = q @ w_q (512 blocks, HILO) + K/V tables (32 blocks, KV)
  gemm3<3, MODE_QPKV><<<dim3(72, 8, 1), 256, 65536, stream>>>(
      qh, ql, wqt_h, wqt_l, 0, 0,
      (float*)0, qph, qpl, (float*)0, (int*)0,
      memh, meml, wkvT_h, wkvT_l, Ktab, VtT);

  // 3. approx scores (1-product) + top-2-per-half candidates
  gemm3<1, MODE_ARGMAX><<<dim3(16, 8, 4), 256, 32768, stream>>>(
      qph, (const __bf16*)0, memh, (const __bf16*)0, 2048, (long)NPAD * DIM,
      (float*)0, (__bf16*)0, (__bf16*)0, pv, pi,
      (const __bf16*)0, (const __bf16*)0, (const __bf16*)0, (const __bf16*)0,
      (__bf16*)0, (__bf16*)0);

  // 4. exact rescore of candidates -> exact argmax
  knn_rescore<<<dim3(ROWS / 4), 256, 0, stream>>>(qph, qpl, mem, pv, pi, idx);

  // 5. counts -> log2 bias
  hist_lc<<<dim3(BATCH), 256, 0, stream>>>(idx, lc);

  // 6. attention over the table (2 heads/block, 48 KiB LDS)
  attn_table<<<dim3(SEQ / 128, NHEAD / 2, BATCH), 256, 49152, stream>>>(
      qph, Ktab, VtT, lc, attn_bf);

  // 7. out = attn @ w_concat (overwrites the qh/ql scratch in d_out)
  gemm3<1, MODE_C><<<dim3(64, 8, 1), 256, 32768, stream>>>(
      attn_bf, (const __bf16*)0, wct, (const __bf16*)0, 0, 0,
      out, (__bf16*)0, (__bf16*)0, (float*)0, (int*)0,
      (const __bf16*)0, (const __bf16*)0, (const __bf16*)0, (const __bf16*)0,
      (__bf16*)0, (__bf16*)0);
}